// Round 1
// baseline (385.986 us; speedup 1.0000x reference)
//
#include <hip/hip_runtime.h>

// out[b,o,s,p] = bias[o] + sum_i W[o,i] * x[b,i,s,p] * (1 + 0.1*eps[n,o,i])
//   n = b*1024 + s*16 + p  (sp = s*16+p)
// B=8, I=64, S=64, P=16, O=128, N=8192.
// eps is 256 MB -> pure HBM-streaming kernel. 16 lanes x float4 per (n,o) row;
// block = 256 threads owns 16 consecutive n (512 KB contiguous eps slab).

#define NOISE 0.1f

__global__ __launch_bounds__(256) void noise_conv_kernel(
    const float* __restrict__ x,     // [8, 64, 64, 16]
    const float* __restrict__ W,     // [128, 64]
    const float* __restrict__ bias,  // [128]
    const float* __restrict__ eps,   // [8192, 128, 64]
    float* __restrict__ out)         // [8, 128, 64, 16]
{
    constexpr int I = 64, O = 128, SP = 1024, NT = 16;
    __shared__ float lds_x[NT * I];    // [dn][i]
    __shared__ float lds_out[O * NT];  // [o][dn]

    const int tid = threadIdx.x;
    const int g = tid >> 4;   // group 0..15 (one row per group per step)
    const int l = tid & 15;   // lane in group: handles i = 4l..4l+3

    const int n0  = blockIdx.x * NT;
    const int b   = n0 >> 10;
    const int sp0 = n0 & 1023;

    // Stage x_t[n0+dn][i] = x[b*65536 + i*1024 + sp0+dn] into LDS.
    // Map e -> (i = e>>4, dn = e&15) so global reads are 64B-contiguous runs.
    const float* xb = x + b * (I * SP) + sp0;
    #pragma unroll
    for (int e = tid; e < NT * I; e += 256) {
        int i = e >> 4, dn = e & 15;
        lds_x[dn * I + i] = xb[i * SP + dn];
    }

    // W fragments in registers: wf[m] = W[m*16+g][4l..4l+3]
    float4 wf[8];
    #pragma unroll
    for (int k = 0; k < 8; ++k)
        wf[k] = *(const float4*)(W + (k * 16 + g) * I + l * 4);

    __syncthreads();

    // eps[(n0+dn)*8192 + (m*16+g)*64 + 4l]
    const float* eps_base = eps + (size_t)n0 * 8192 + g * 64 + l * 4;

    for (int dn = 0; dn < NT; ++dn) {
        const float4 xv = *(const float4*)(lds_x + dn * I + l * 4);
        const float* ep = eps_base + dn * 8192;
        #pragma unroll
        for (int m = 0; m < 8; ++m) {
            float4 e4 = *(const float4*)(ep + m * 1024);
            float4 w4 = wf[m];
            float t0 = w4.x * xv.x, t1 = w4.y * xv.y,
                  t2 = w4.z * xv.z, t3 = w4.w * xv.w;
            float acc = t0 * fmaf(NOISE, e4.x, 1.0f)
                      + t1 * fmaf(NOISE, e4.y, 1.0f)
                      + t2 * fmaf(NOISE, e4.z, 1.0f)
                      + t3 * fmaf(NOISE, e4.w, 1.0f);
            // reduce across the 16-lane group (stays inside wave64)
            acc += __shfl_xor(acc, 1);
            acc += __shfl_xor(acc, 2);
            acc += __shfl_xor(acc, 4);
            acc += __shfl_xor(acc, 8);
            if (l == 0)
                lds_out[(m * 16 + g) * NT + dn] = acc;
        }
    }
    __syncthreads();

    // out[b*131072 + o*1024 + sp0 + dn], full 64B lines per o row
    float* ob = out + b * (O * SP) + sp0;
    #pragma unroll
    for (int q = tid; q < (O * NT) / 4; q += 256) {
        int o = q >> 2, j = (q & 3) * 4;
        float4 v = *(const float4*)(lds_out + o * NT + j);
        float bo = bias[o];
        v.x += bo; v.y += bo; v.z += bo; v.w += bo;
        *(float4*)(ob + o * SP + j) = v;
    }
}

extern "C" void kernel_launch(void* const* d_in, const int* in_sizes, int n_in,
                              void* d_out, int out_size, void* d_ws, size_t ws_size,
                              hipStream_t stream) {
    const float* x    = (const float*)d_in[0];  // 524288
    const float* W    = (const float*)d_in[1];  // 8192
    const float* bias = (const float*)d_in[2];  // 128
    const float* eps  = (const float*)d_in[3];  // 67108864
    float* out = (float*)d_out;                 // 1048576

    noise_conv_kernel<<<512, 256, 0, stream>>>(x, W, bias, eps, out);
}

// Round 2
// 370.970 us; speedup vs baseline: 1.0405x; 1.0405x over previous
//
#include <hip/hip_runtime.h>

// out[b,o,s,p] = bias[o] + sum_i W[o,i] * x[b,i,s,p] * (1 + 0.1*eps[n,o,i])
//   n = b*1024 + s*16 + p  (sp = s*16+p)
// B=8, I=64, S=64, P=16, O=128, N=8192. eps is 256 MB -> HBM-streaming.
//
// Round 2: occupancy fix. 2048 blocks (8 n-rows x half-O each, 128 KB eps
// footprint per block) -> 8 blocks/CU, 8 waves/SIMD to hide the shfl-chain
// and HBM latency. 16 lanes x float4 per (n,o) row keeps eps reads 1KB-
// contiguous per wave.

#define NOISE 0.1f

__global__ __launch_bounds__(256) void noise_conv_kernel(
    const float* __restrict__ x,     // [8, 64, 64, 16]
    const float* __restrict__ W,     // [128, 64]
    const float* __restrict__ bias,  // [128]
    const float* __restrict__ eps,   // [8192, 128, 64]
    float* __restrict__ out)         // [8, 128, 64, 16]
{
    constexpr int I = 64, O = 128, SP = 1024;
    constexpr int NT = 8;   // n-rows per block
    constexpr int MH = 4;   // m-steps per block (MH*16 = 64 o-rows)
    __shared__ float lds_x[NT * I];        // [dn][i]
    __shared__ float lds_out[MH * 16 * NT]; // [o_loc][dn]

    const int tid = threadIdx.x;
    const int g = tid >> 4;   // group 0..15
    const int l = tid & 15;   // lane in group: i = 4l..4l+3

    const int mh = blockIdx.x & 1;         // which o-half
    const int ns = blockIdx.x >> 1;        // n-slab
    const int n0  = ns * NT;
    const int b   = n0 >> 10;
    const int sp0 = n0 & 1023;
    const int o_base = mh * 64;

    // Stage x[n0+dn][i] into LDS (runs of 8 contiguous floats per i).
    const float* xb = x + b * (I * SP) + sp0;
    #pragma unroll
    for (int e = tid; e < NT * I; e += 256) {
        int i = e >> 3, dn = e & 7;
        lds_x[dn * I + i] = xb[i * SP + dn];
    }

    // W fragments in registers: wf[m] = W[o_base + m*16 + g][4l..4l+3]
    float4 wf[MH];
    #pragma unroll
    for (int k = 0; k < MH; ++k)
        wf[k] = *(const float4*)(W + (o_base + k * 16 + g) * I + l * 4);

    __syncthreads();

    // eps[(n0+dn)*8192 + (o_base + m*16 + g)*64 + 4l]
    const float* eps_base = eps + (size_t)n0 * 8192 + (o_base + g) * 64 + l * 4;

    #pragma unroll
    for (int dn = 0; dn < NT; ++dn) {
        const float4 xv = *(const float4*)(lds_x + dn * I + l * 4);
        const float* ep = eps_base + dn * 8192;
        #pragma unroll
        for (int m = 0; m < MH; ++m) {
            float4 e4 = *(const float4*)(ep + m * 1024);
            float4 w4 = wf[m];
            float t0 = w4.x * xv.x, t1 = w4.y * xv.y,
                  t2 = w4.z * xv.z, t3 = w4.w * xv.w;
            float acc = t0 * fmaf(NOISE, e4.x, 1.0f)
                      + t1 * fmaf(NOISE, e4.y, 1.0f)
                      + t2 * fmaf(NOISE, e4.z, 1.0f)
                      + t3 * fmaf(NOISE, e4.w, 1.0f);
            acc += __shfl_xor(acc, 1);
            acc += __shfl_xor(acc, 2);
            acc += __shfl_xor(acc, 4);
            acc += __shfl_xor(acc, 8);
            if (l == 0)
                lds_out[(m * 16 + g) * NT + dn] = acc;
        }
    }
    __syncthreads();

    // out[b*131072 + (o_base+o_loc)*1024 + sp0 + dn]; 32B per o-row
    float* ob = out + b * (O * SP) + o_base * SP + sp0;
    if (tid < (MH * 16 * NT) / 4) {
        int o_loc = tid >> 1, j = (tid & 1) * 4;
        float4 v = *(const float4*)(lds_out + o_loc * NT + j);
        float bo = bias[o_base + o_loc];
        v.x += bo; v.y += bo; v.z += bo; v.w += bo;
        *(float4*)(ob + o_loc * SP + j) = v;
    }
}

extern "C" void kernel_launch(void* const* d_in, const int* in_sizes, int n_in,
                              void* d_out, int out_size, void* d_ws, size_t ws_size,
                              hipStream_t stream) {
    const float* x    = (const float*)d_in[0];  // 524288
    const float* W    = (const float*)d_in[1];  // 8192
    const float* bias = (const float*)d_in[2];  // 128
    const float* eps  = (const float*)d_in[3];  // 67108864
    float* out = (float*)d_out;                 // 1048576

    noise_conv_kernel<<<2048, 256, 0, stream>>>(x, W, bias, eps, out);
}

// Round 4
// 368.972 us; speedup vs baseline: 1.0461x; 1.0054x over previous
//
#include <hip/hip_runtime.h>

// out[b,o,s,p] = bias[o] + sum_i W[o,i] * x[b,i,s,p] * (1 + 0.1*eps[n,o,i])
//   n = b*1024 + s*16 + p  (sp = s*16+p)
// B=8, I=64, S=64, P=16, O=128, N=8192. eps is 256 MB -> HBM-streaming.
//
// Round 4: round-3 DPP reduction, fixed for the constant-integer requirement
// of __builtin_amdgcn_update_dpp (ctrl is now a template parameter).
// 16-lane reduction = 4 DPP VALU ops (quad_perm xor1/xor2, row_half_mirror,
// row_mirror) — zero lgkmcnt traffic in the hot loop. Per-dn invariants
// (u = 0.1*W*x, bsum = dot(W,x)) hoisted: each eps-float4 costs 4 fmaf + 4 DPP.

#define NOISE 0.1f

template <int CTRL>
__device__ __forceinline__ float dpp_add(float v) {
    int p = __builtin_amdgcn_update_dpp(0, __float_as_int(v), CTRL, 0xF, 0xF, false);
    return v + __int_as_float(p);
}

__global__ __launch_bounds__(256) void noise_conv_kernel(
    const float* __restrict__ x,     // [8, 64, 64, 16]
    const float* __restrict__ W,     // [128, 64]
    const float* __restrict__ bias,  // [128]
    const float* __restrict__ eps,   // [8192, 128, 64]
    float* __restrict__ out)         // [8, 128, 64, 16]
{
    constexpr int I = 64, O = 128, SP = 1024;
    constexpr int NT = 8;   // n-rows per block
    constexpr int MH = 4;   // m-steps per block (MH*16 = 64 o-rows)
    __shared__ float lds_x[NT * I];         // [dn][i]
    __shared__ float lds_out[MH * 16 * NT]; // [o_loc][dn]

    const int tid = threadIdx.x;
    const int g = tid >> 4;   // group 0..15 (16-lane DPP row)
    const int l = tid & 15;   // lane in group: i = 4l..4l+3

    const int mh = blockIdx.x & 1;   // o-half
    const int ns = blockIdx.x >> 1;  // n-slab
    const int n0  = ns * NT;
    const int b   = n0 >> 10;
    const int sp0 = n0 & 1023;
    const int o_base = mh * 64;

    // Stage x[n0+dn][i] into LDS (runs of 8 contiguous floats per i).
    const float* xb = x + b * (I * SP) + sp0;
    #pragma unroll
    for (int e = tid; e < NT * I; e += 256) {
        int i = e >> 3, dn = e & 7;
        lds_x[dn * I + i] = xb[i * SP + dn];
    }

    // W fragments in registers: wf[m] = W[o_base + m*16 + g][4l..4l+3]
    float4 wf[MH];
    #pragma unroll
    for (int k = 0; k < MH; ++k)
        wf[k] = *(const float4*)(W + (o_base + k * 16 + g) * I + l * 4);

    __syncthreads();

    // eps[(n0+dn)*8192 + (o_base + m*16 + g)*64 + 4l]
    const float* eps_base = eps + (size_t)n0 * 8192 + (o_base + g) * 64 + l * 4;

    #pragma unroll
    for (int dn = 0; dn < NT; ++dn) {
        const float4 xv = *(const float4*)(lds_x + dn * I + l * 4);
        const float* ep = eps_base + dn * 8192;

        // per-dn invariants: u = NOISE*W*x (elementwise), bsum = dot(W,x)
        float4 u[MH];
        float bsum[MH];
        #pragma unroll
        for (int m = 0; m < MH; ++m) {
            float4 w4 = wf[m];
            u[m].x = NOISE * w4.x * xv.x;
            u[m].y = NOISE * w4.y * xv.y;
            u[m].z = NOISE * w4.z * xv.z;
            u[m].w = NOISE * w4.w * xv.w;
            bsum[m] = w4.x * xv.x + w4.y * xv.y + w4.z * xv.z + w4.w * xv.w;
        }

        #pragma unroll
        for (int m = 0; m < MH; ++m) {
            float4 e4 = *(const float4*)(ep + m * 1024);
            float acc = fmaf(u[m].x, e4.x,
                        fmaf(u[m].y, e4.y,
                        fmaf(u[m].z, e4.z,
                        fmaf(u[m].w, e4.w, bsum[m]))));
            // 16-lane reduction entirely on the VALU pipe (DPP):
            acc = dpp_add<0xB1>(acc);    // quad_perm [1,0,3,2]  (xor 1)
            acc = dpp_add<0x4E>(acc);    // quad_perm [2,3,0,1]  (xor 2)
            acc = dpp_add<0x141>(acc);   // row_half_mirror      (xor within 8)
            acc = dpp_add<0x140>(acc);   // row_mirror           (cross 8-halves)
            if (l == 0)
                lds_out[(m * 16 + g) * NT + dn] = acc;
        }
    }
    __syncthreads();

    // out[b*131072 + (o_base+o_loc)*1024 + sp0 + dn]; 32B per o-row
    float* ob = out + b * (O * SP) + o_base * SP + sp0;
    if (tid < (MH * 16 * NT) / 4) {
        int o_loc = tid >> 1, j = (tid & 1) * 4;
        float4 v = *(const float4*)(lds_out + o_loc * NT + j);
        float bo = bias[o_base + o_loc];
        v.x += bo; v.y += bo; v.z += bo; v.w += bo;
        *(float4*)(ob + o_loc * SP + j) = v;
    }
}

extern "C" void kernel_launch(void* const* d_in, const int* in_sizes, int n_in,
                              void* d_out, int out_size, void* d_ws, size_t ws_size,
                              hipStream_t stream) {
    const float* x    = (const float*)d_in[0];  // 524288
    const float* W    = (const float*)d_in[1];  // 8192
    const float* bias = (const float*)d_in[2];  // 128
    const float* eps  = (const float*)d_in[3];  // 67108864
    float* out = (float*)d_out;                 // 1048576

    noise_conv_kernel<<<2048, 256, 0, stream>>>(x, W, bias, eps, out);
}

// Round 5
// 366.688 us; speedup vs baseline: 1.0526x; 1.0062x over previous
//
#include <hip/hip_runtime.h>

// out[b,o,s,p] = bias[o] + sum_i W[o,i]*x[b,i,s,p]*(1 + 0.1*eps[n,o,i])
//   n = b*1024 + s*16 + p. B=8,I=64,S=64,P=16,O=128,N=8192. eps=256MB stream.
//
// Round 5: remove ALL cross-lane ops and predication from the hot loop.
// Per (dn,m) step each lane does: 1 independent global_load_dwordx4 +
// ~12 straight-line VALU + 1 unconditional ds_write_b32 (its partial).
// 32 independent chains/wave -> max loads in flight. The 16-lane reduction
// is deferred to a small LDS epilogue after one barrier.

#define NOISE 0.1f

__global__ __launch_bounds__(256) void noise_conv_kernel(
    const float* __restrict__ x,     // [8, 64, 64, 16]
    const float* __restrict__ W,     // [128, 64]
    const float* __restrict__ bias,  // [128]
    const float* __restrict__ eps,   // [8192, 128, 64]
    float* __restrict__ out)         // [8, 128, 64, 16]
{
    constexpr int I = 64, O = 128, SP = 1024;
    constexpr int NT = 8;   // n-rows per block
    constexpr int MH = 4;   // m-steps (16 o each) -> 64 o per block
    constexpr int NOUT = NT * MH * 16;  // 512 outputs per block
    __shared__ float lds_x[NT * I];     // 2 KB
    __shared__ float lds_p[NOUT * 17];  // partials, 17-dword pitch (bank-safe), 34 KB

    const int tid = threadIdx.x;
    const int g = tid >> 4;   // 0..15
    const int l = tid & 15;   // lane-in-row: i = 4l..4l+3

    const int mh = blockIdx.x & 1;   // o-half
    const int ns = blockIdx.x >> 1;  // n-slab
    const int n0  = ns * NT;
    const int b   = n0 >> 10;
    const int sp0 = n0 & 1023;
    const int o_base = mh * 64;

    // Stage x[n0+dn][i] into LDS (32B contiguous runs, one-time).
    const float* xb = x + b * (I * SP) + sp0;
    #pragma unroll
    for (int e = tid; e < NT * I; e += 256) {
        int i = e >> 3, dn = e & 7;
        lds_x[dn * I + i] = xb[i * SP + dn];
    }

    // W fragments: wf[m] = W[o_base + m*16 + g][4l..4l+3]
    float4 wf[MH];
    #pragma unroll
    for (int k = 0; k < MH; ++k)
        wf[k] = *(const float4*)(W + (o_base + k * 16 + g) * I + l * 4);

    __syncthreads();

    // eps[(n0+dn)*8192 + (o_base + m*16 + g)*64 + 4l] — each wave-load is
    // 1KB fully contiguous (16 lanes x float4 x 4 rows).
    const float* eps_base = eps + (size_t)n0 * 8192 + (o_base + g) * 64 + l * 4;

    #pragma unroll
    for (int dn = 0; dn < NT; ++dn) {
        const float4 xv = *(const float4*)(lds_x + dn * I + l * 4);
        const float* ep = eps_base + dn * 8192;
        #pragma unroll
        for (int m = 0; m < MH; ++m) {
            float4 e4 = *(const float4*)(ep + m * 1024);
            float4 w4 = wf[m];
            float wx0 = w4.x * xv.x, wx1 = w4.y * xv.y,
                  wx2 = w4.z * xv.z, wx3 = w4.w * xv.w;
            float s = (wx0 + wx1) + (wx2 + wx3);
            float t = fmaf(wx3, e4.w,
                      fmaf(wx2, e4.z,
                      fmaf(wx1, e4.y, wx0 * e4.x)));
            float acc = fmaf(NOISE, t, s);
            // unconditional per-lane partial store; banks ~2-3 way (free-ish)
            lds_p[((dn * MH + m) * 16 + g) * 17 + l] = acc;
        }
    }
    __syncthreads();

    // Epilogue: 512 outputs, 2 per thread. out_local = (dn*MH+m)*16+g.
    // Reads at 17-dword pitch -> conflict-free (17 odd).
    float* ob = out + b * (O * SP) + sp0;
    #pragma unroll
    for (int r = 0; r < 2; ++r) {
        int ol = tid + r * 256;
        const float* pp = lds_p + ol * 17;
        float ssum = 0.f;
        #pragma unroll
        for (int j = 0; j < 16; ++j) ssum += pp[j];
        int gg = ol & 15, mm = (ol >> 4) & 3, dn = ol >> 6;
        int o = o_base + mm * 16 + gg;
        ob[o * SP + dn] = ssum + bias[o];
    }
}

extern "C" void kernel_launch(void* const* d_in, const int* in_sizes, int n_in,
                              void* d_out, int out_size, void* d_ws, size_t ws_size,
                              hipStream_t stream) {
    const float* x    = (const float*)d_in[0];  // 524288
    const float* W    = (const float*)d_in[1];  // 8192
    const float* bias = (const float*)d_in[2];  // 128
    const float* eps  = (const float*)d_in[3];  // 67108864
    float* out = (float*)d_out;                 // 1048576

    noise_conv_kernel<<<2048, 256, 0, stream>>>(x, W, bias, eps, out);
}